// Round 7
// baseline (16.436 us; speedup 1.0000x reference)
//
#include <hip/hip_runtime.h>

// Problem geometry (fixed by the reference module config)
#define IC    8
#define OC    16
#define H     32
#define W     32
#define BATCH 64
#define WCOLS 9248          // IC*34*34
#define XSTR  36            // LDS row stride (floats): 16B-aligned rows
#define PLANE (34 * XSTR)   // 1224 floats per channel plane
#define NGRP  2448          // 9 groups * 272 rows (8 ic * 34 padded rows)

// Unaligned-capable float4 view (4B alignment) for shifted global loads.
struct __attribute__((packed)) f4u { float x, y, z, w; };

// Block = (batch, oc-pair), 256 threads. Thread = 1x4 strip x 2 ocs.
// All LDS traffic vectorized with non-divergent, bank-uniform patterns.
__global__ __launch_bounds__(256, 2) void conv_v7_kernel(
    const float* __restrict__ x,       // [B, IC*H*W]
    const float* __restrict__ weight,  // [OC*OH*OW, WCOLS] Toeplitz
    const float* __restrict__ bias,    // [OC*OH*OW]
    float* __restrict__ out)           // [B, OC*OH*OW]
{
    __shared__ float wk[16 * 12];      // [(os*8+ic)*12 + kh*3+kw], b128-hoistable
    __shared__ float xs[IC * PLANE];   // 39168 B padded planes (left-pad layout)

    const int tid = threadIdx.x;
    const int blk = blockIdx.x;
    const int b   = blk >> 3;          // batch
    const int oc0 = (blk & 7) << 1;    // first oc of the pair

    // ---- weights -> LDS (144 gathered global reads, L2-hot across blocks) ----
    if (tid < 144) {
        const int os = tid / 72;
        const int k  = tid - os * 72;      // 0..71
        const int ic = k / 9;
        const int r  = k - ic * 9;         // kh*3+kw
        const int kh = r / 3;
        const int kw = r - kh * 3;
        wk[(os * 8 + ic) * 12 + r] =
            weight[(size_t)((oc0 + os) << 10) * WCOLS + (ic * 34 + kh) * 34 + kw];
    }

    // ---- stage padded image: group-major (wave-uniform g), aligned b128 writes ----
    // padded row (34 cols + 2 junk): col0 = left pad, cols 1..32 = x0..x31, col33 = right pad.
    // group g covers cols 4g..4g+3, i.e. values [x(4g-1), x(4g), x(4g+1), x(4g+2)].
    const float* xb = x + ((size_t)b << 13);
    #pragma unroll
    for (int it = 0; it < 10; ++it) {
        const int idx = tid + (it << 8);
        if (idx < NGRP) {
            const int g    = idx / 272;          // 0..8, wave-uniform (+/-1 at seams)
            const int rid  = idx - g * 272;      // 0..271
            const int ic   = rid / 34;
            const int row  = rid - ic * 34;      // padded row 0..33
            const bool zr  = (row == 0) | (row == 33);
            const int dr   = zr ? 0 : (row - 1); // clamped data row
            const float* rb = xb + (ic << 10) + (dr << 5);
            float4 v;
            if (g == 0) {
                const float4 a = *(const float4*)rb;            // x0..x3 (aligned)
                v = make_float4(0.f, a.x, a.y, a.z);
            } else if (g == 8) {
                const float4 a = *(const float4*)(rb + 28);     // x28..x31 (aligned)
                v = make_float4(a.w, 0.f, 0.f, 0.f);
            } else {
                const f4u a = *(const f4u*)(rb + (g << 2) - 1); // x(4g-1).. (4B-aligned)
                v = make_float4(a.x, a.y, a.z, a.w);
            }
            if (zr) v = make_float4(0.f, 0.f, 0.f, 0.f);
            *(float4*)&xs[ic * PLANE + row * XSTR + (g << 2)] = v;   // aligned b128
        }
    }
    __syncthreads();

    // ---- compute: 1x4 strip at (oh, ow0..ow0+3) for both ocs ----
    const int oh   = tid >> 3;         // 0..31
    const int ow0  = (tid & 7) << 2;   // 0,4,...,28
    const int oidx = (oh << 5) + ow0;

    const float4 bv0 = *(const float4*)(bias + (oc0 << 10) + oidx);
    const float4 bv1 = *(const float4*)(bias + ((oc0 + 1) << 10) + oidx);
    float a00 = bv0.x, a01 = bv0.y, a02 = bv0.z, a03 = bv0.w;
    float a10 = bv1.x, a11 = bv1.y, a12 = bv1.z, a13 = bv1.w;

    const float4* wk4 = (const float4*)wk;

    #pragma unroll
    for (int ic = 0; ic < IC; ++ic) {
        // broadcast (uniform-address) b128 weight hoists: 6 per ic
        const float4 A0 = wk4[ic * 3 + 0];
        const float4 A1 = wk4[ic * 3 + 1];
        const float4 A2 = wk4[ic * 3 + 2];
        const float4 B0 = wk4[(8 + ic) * 3 + 0];
        const float4 B1 = wk4[(8 + ic) * 3 + 1];
        const float4 B2 = wk4[(8 + ic) * 3 + 2];
        const float wA[9] = {A0.x, A0.y, A0.z, A0.w, A1.x, A1.y, A1.z, A1.w, A2.x};
        const float wB[9] = {B0.x, B0.y, B0.z, B0.w, B1.x, B1.y, B1.z, B1.w, B2.x};

        #pragma unroll
        for (int kh = 0; kh < 3; ++kh) {
            const float* rp = &xs[ic * PLANE + (oh + kh) * XSTR + ow0];
            const float4 va = *(const float4*)rp;        // aligned b128
            const float2 vb = *(const float2*)(rp + 4);  // aligned b64
            const float v0 = va.x, v1 = va.y, v2 = va.z, v3 = va.w;
            const float v4 = vb.x, v5 = vb.y;
            {
                const float w0 = wA[kh * 3], w1 = wA[kh * 3 + 1], w2 = wA[kh * 3 + 2];
                a00 += v0 * w0 + v1 * w1 + v2 * w2;
                a01 += v1 * w0 + v2 * w1 + v3 * w2;
                a02 += v2 * w0 + v3 * w1 + v4 * w2;
                a03 += v3 * w0 + v4 * w1 + v5 * w2;
            }
            {
                const float w0 = wB[kh * 3], w1 = wB[kh * 3 + 1], w2 = wB[kh * 3 + 2];
                a10 += v0 * w0 + v1 * w1 + v2 * w2;
                a11 += v1 * w0 + v2 * w1 + v3 * w2;
                a12 += v2 * w0 + v3 * w1 + v4 * w2;
                a13 += v3 * w0 + v4 * w1 + v5 * w2;
            }
        }
    }

    float* o0 = out + (size_t)(((b << 4) + oc0) << 10) + oidx;
    *(float4*)o0          = make_float4(a00, a01, a02, a03);
    *(float4*)(o0 + 1024) = make_float4(a10, a11, a12, a13);
}

extern "C" void kernel_launch(void* const* d_in, const int* in_sizes, int n_in,
                              void* d_out, int out_size, void* d_ws, size_t ws_size,
                              hipStream_t stream) {
    const float* x      = (const float*)d_in[0];  // enc_x  [64, 8192]
    const float* weight = (const float*)d_in[1];  // weight [16384, 9248]
    const float* bias   = (const float*)d_in[2];  // bias   [16384]
    // d_in[3] = pad_mat: realized structurally via the left-pad LDS layout.
    float* out = (float*)d_out;                   // [64, 16384]

    conv_v7_kernel<<<dim3(BATCH * 8), dim3(256), 0, stream>>>(x, weight, bias, out);
}

// Round 8
// 11.390 us; speedup vs baseline: 1.4430x; 1.4430x over previous
//
#include <hip/hip_runtime.h>

// Problem geometry (fixed by the reference module config)
#define IC    8
#define OC    16
#define H     32
#define W     32
#define PH    34
#define PW    34
#define BATCH 64
#define WCOLS (IC * PH * PW)   // 9248
#define XSTR  35               // LDS row stride (floats): odd -> <=2-way bank alias (free)
#define PLANE (PH * XSTR)      // 34*35 = 1190 floats per input-channel plane

// r2 structure: block = (batch, oc-pair), 256 threads, thread = 1x4 strip x 2 ocs.
// ONLY change vs r2: weights come from wave-uniform global loads (scalar s_load
// path) instead of a 144-lane gather + per-thread 144-read LDS hoist.
__global__ __launch_bounds__(256, 2) void conv_v8_kernel(
    const float* __restrict__ x,       // [B, IC*H*W]
    const float* __restrict__ weight,  // [OC*OH*OW, WCOLS] Toeplitz
    const float* __restrict__ bias,    // [OC*OH*OW]
    float* __restrict__ out)           // [B, OC*OH*OW]
{
    __shared__ float xs[IC * PLANE];    // zero-padded input planes (38.1 KB)

    const int tid = threadIdx.x;
    const int blk = blockIdx.x;
    const int b   = blk >> 3;           // batch index
    const int oc0 = (blk & 7) << 1;     // first oc of the pair

    // ---- zero ONLY the halo (rows 0/33 full-ish, cols 0/33 of rows 1..32) ----
    for (int i = tid; i < IC * 132; i += 256) {
        const int p = i / 132;
        const int r = i - p * 132;
        int row, col;
        if (r < 34)       { row = 0;       col = r;      }
        else if (r < 68)  { row = 33;      col = r - 34; }
        else if (r < 100) { row = r - 67;  col = 0;      }   // rows 1..32
        else              { row = r - 99;  col = 33;     }
        xs[p * PLANE + row * XSTR + col] = 0.0f;
    }

    // ---- stage x[b] into the interior (coalesced float4 global loads) ----
    const float4* xg = (const float4*)(x + (size_t)b * (IC * H * W));
    #pragma unroll
    for (int i = 0; i < 8; ++i) {
        const int k   = tid + (i << 8);     // float4 index, 0..2047
        const float4 v = xg[k];
        const int ic  = k >> 8;             // 256 float4 per channel plane
        const int rem = k & 255;
        const int h   = rem >> 3;           // 8 float4 per row
        const int w4  = (rem & 7) << 2;
        float* dst = &xs[ic * PLANE + (h + 1) * XSTR + (w4 + 1)];
        dst[0] = v.x; dst[1] = v.y; dst[2] = v.z; dst[3] = v.w;
    }
    __syncthreads();

    // ---- wave-uniform weight bases (blockIdx-only -> scalar loads) ----
    const float* wp0 = weight + (size_t)(oc0 << 10) * WCOLS;
    const float* wp1 = wp0 + ((size_t)1024) * WCOLS;

    // ---- each thread: 1x4 output strip at (oh, ow0..ow0+3), both ocs ----
    const int oh   = tid >> 3;          // 0..31
    const int ow0  = (tid & 7) << 2;    // 0,4,...,28
    const int oidx = (oh << 5) + ow0;

    const float4 b0 = *(const float4*)(bias + (oc0 << 10) + oidx);
    const float4 b1 = *(const float4*)(bias + ((oc0 + 1) << 10) + oidx);
    float a00 = b0.x, a01 = b0.y, a02 = b0.z, a03 = b0.w;
    float a10 = b1.x, a11 = b1.y, a12 = b1.z, a13 = b1.w;

    #pragma unroll
    for (int ic = 0; ic < IC; ++ic) {
        // uniform global loads, compile-time offsets -> s_load + broadcast
        float wA[9], wB[9];
        #pragma unroll
        for (int kh = 0; kh < 3; ++kh)
            #pragma unroll
            for (int kw = 0; kw < 3; ++kw) {
                wA[kh * 3 + kw] = wp0[(ic * PH + kh) * PW + kw];
                wB[kh * 3 + kw] = wp1[(ic * PH + kh) * PW + kw];
            }

        #pragma unroll
        for (int kh = 0; kh < 3; ++kh) {
            const float* row = &xs[ic * PLANE + (oh + kh) * XSTR + ow0];
            const float v0 = row[0], v1 = row[1], v2 = row[2];
            const float v3 = row[3], v4 = row[4], v5 = row[5];
            {
                const float w0 = wA[kh * 3], w1 = wA[kh * 3 + 1], w2 = wA[kh * 3 + 2];
                a00 += v0 * w0 + v1 * w1 + v2 * w2;
                a01 += v1 * w0 + v2 * w1 + v3 * w2;
                a02 += v2 * w0 + v3 * w1 + v4 * w2;
                a03 += v3 * w0 + v4 * w1 + v5 * w2;
            }
            {
                const float w0 = wB[kh * 3], w1 = wB[kh * 3 + 1], w2 = wB[kh * 3 + 2];
                a10 += v0 * w0 + v1 * w1 + v2 * w2;
                a11 += v1 * w0 + v2 * w1 + v3 * w2;
                a12 += v2 * w0 + v3 * w1 + v4 * w2;
                a13 += v3 * w0 + v4 * w1 + v5 * w2;
            }
        }
    }

    float* o0 = out + (size_t)(((b << 4) + oc0) << 10) + oidx;
    *(float4*)o0          = make_float4(a00, a01, a02, a03);
    *(float4*)(o0 + 1024) = make_float4(a10, a11, a12, a13);
}

extern "C" void kernel_launch(void* const* d_in, const int* in_sizes, int n_in,
                              void* d_out, int out_size, void* d_ws, size_t ws_size,
                              hipStream_t stream) {
    const float* x      = (const float*)d_in[0];  // enc_x  [64, 8192]
    const float* weight = (const float*)d_in[1];  // weight [16384, 9248]
    const float* bias   = (const float*)d_in[2];  // bias   [16384]
    // d_in[3] = pad_mat: realized structurally via the LDS halo.
    float* out = (float*)d_out;                   // [64, 16384]

    conv_v8_kernel<<<dim3(BATCH * 8), dim3(256), 0, stream>>>(x, weight, bias, out);
}

// Round 9
// 11.111 us; speedup vs baseline: 1.4792x; 1.0251x over previous
//
#include <hip/hip_runtime.h>

// Problem geometry (fixed by the reference module config)
#define IC    8
#define OC    16
#define H     32
#define W     32
#define PH    34
#define PW    34
#define OH    32
#define OW    32
#define BATCH 64
#define WCOLS (IC * PH * PW)   // 9248 columns of the Toeplitz weight
#define XSTR  35               // LDS row stride (floats): odd -> <=2-way bank alias (free)
#define PLANE (PH * XSTR)      // 34*35 = 1190 floats per input-channel plane

// One block per (batch, oc-pair); 256 threads; each thread computes a 1x4 strip
// for BOTH ocs of the pair (x-window LDS reads shared across the 2 ocs).
// Measured best structure of the session (r2, 10.94 us): LDS-staged image with
// halo-only zeroing, LDS-hoisted weights (keeps lgkmcnt on the DS path only),
// scalar window reads at odd stride (conflict-free), 576 unrolled FMAs.
__global__ __launch_bounds__(256, 2) void conv_toeplitz_kernel(
    const float* __restrict__ x,       // [B, IC*H*W]
    const float* __restrict__ weight,  // [OC*OH*OW, WCOLS] Toeplitz
    const float* __restrict__ bias,    // [OC*OH*OW]
    float* __restrict__ out)           // [B, OC*OH*OW]
{
    __shared__ float wk[2][IC * 9];     // kernel slices for the oc pair
    __shared__ float xs[IC * PLANE];    // zero-padded input planes

    const int tid = threadIdx.x;
    const int blk = blockIdx.x;
    const int b   = blk >> 3;           // batch index
    const int oc0 = (blk & 7) << 1;     // first oc of the pair

    // --- recover conv kernels from the Toeplitz rows for (oc0, oc0+1) ---
    if (tid < 144) {
        const int os = tid / 72;                // which oc of the pair
        const int k  = tid - os * 72;           // 0..71
        const int ic = k / 9;
        const int r  = k - ic * 9;
        const int kh = r / 3;
        const int kw = r - kh * 3;
        wk[os][k] = weight[(size_t)((oc0 + os) * OH * OW) * WCOLS
                           + (ic * PH + kh) * PW + kw];
    }

    // --- zero ONLY the halo (rows 0/33 full, cols 0/33 of rows 1..32) ---
    for (int i = tid; i < IC * 134; i += 256) {
        const int plane = i / 134;
        const int r     = i - plane * 134;
        int row, col;
        if (r < 35)       { row = 0;           col = r;        }
        else if (r < 70)  { row = 33;          col = r - 35;   }
        else if (r < 102) { row = r - 70 + 1;  col = 0;        }
        else              { row = r - 102 + 1; col = 33;       }
        xs[plane * PLANE + row * XSTR + col] = 0.0f;
    }

    // --- stage x[b] into the interior of the padded LDS tile (coalesced float4 loads) ---
    const float4* xg = (const float4*)(x + (size_t)b * (IC * H * W));
    #pragma unroll
    for (int i = 0; i < 8; ++i) {
        const int k   = tid + i * 256;      // float4 index, 0..2047
        const float4 v = xg[k];
        const int ic  = k >> 8;             // 256 float4 per channel plane
        const int rem = k & 255;
        const int h   = rem >> 3;           // 8 float4 per row
        const int w4  = (rem & 7) << 2;
        float* dst = &xs[ic * PLANE + (h + 1) * XSTR + (w4 + 1)];
        dst[0] = v.x; dst[1] = v.y; dst[2] = v.z; dst[3] = v.w;
    }
    __syncthreads();

    // --- hoist 144 weights into registers (static indexing) ---
    float wreg[2][IC * 9];
    #pragma unroll
    for (int o = 0; o < 2; ++o)
        #pragma unroll
        for (int k = 0; k < IC * 9; ++k)
            wreg[o][k] = wk[o][k];

    // --- each thread: 1x4 output strip at (oh, ow0..ow0+3), both ocs ---
    const int oh   = tid >> 3;          // 0..31
    const int ow0  = (tid & 7) << 2;    // 0,4,...,28
    const int oidx = oh * OW + ow0;

    const float4 b0 = *(const float4*)(bias + oc0 * OH * OW + oidx);
    const float4 b1 = *(const float4*)(bias + (oc0 + 1) * OH * OW + oidx);
    float a00 = b0.x, a01 = b0.y, a02 = b0.z, a03 = b0.w;
    float a10 = b1.x, a11 = b1.y, a12 = b1.z, a13 = b1.w;

    #pragma unroll
    for (int ic = 0; ic < IC; ++ic) {
        #pragma unroll
        for (int kh = 0; kh < 3; ++kh) {
            const float* row = &xs[ic * PLANE + (oh + kh) * XSTR + ow0];
            const float v0 = row[0], v1 = row[1], v2 = row[2];
            const float v3 = row[3], v4 = row[4], v5 = row[5];
            const float w00 = wreg[0][ic * 9 + kh * 3];
            const float w01 = wreg[0][ic * 9 + kh * 3 + 1];
            const float w02 = wreg[0][ic * 9 + kh * 3 + 2];
            const float w10 = wreg[1][ic * 9 + kh * 3];
            const float w11 = wreg[1][ic * 9 + kh * 3 + 1];
            const float w12 = wreg[1][ic * 9 + kh * 3 + 2];
            a00 += v0 * w00 + v1 * w01 + v2 * w02;
            a01 += v1 * w00 + v2 * w01 + v3 * w02;
            a02 += v2 * w00 + v3 * w01 + v4 * w02;
            a03 += v3 * w00 + v4 * w01 + v5 * w02;
            a10 += v0 * w10 + v1 * w11 + v2 * w12;
            a11 += v1 * w10 + v2 * w11 + v3 * w12;
            a12 += v2 * w10 + v3 * w11 + v4 * w12;
            a13 += v3 * w10 + v4 * w11 + v5 * w12;
        }
    }

    float* o0 = out + (size_t)(b * OC + oc0) * (OH * OW) + oidx;
    *(float4*)o0 = make_float4(a00, a01, a02, a03);
    float* o1 = o0 + OH * OW;
    *(float4*)o1 = make_float4(a10, a11, a12, a13);
}

extern "C" void kernel_launch(void* const* d_in, const int* in_sizes, int n_in,
                              void* d_out, int out_size, void* d_ws, size_t ws_size,
                              hipStream_t stream) {
    const float* x      = (const float*)d_in[0];  // enc_x  [64, 8192]
    const float* weight = (const float*)d_in[1];  // weight [16384, 9248]
    const float* bias   = (const float*)d_in[2];  // bias   [16384]
    // d_in[3] = pad_mat: realized structurally via the LDS halo.
    float* out = (float*)d_out;                   // [64, 16384]

    conv_toeplitz_kernel<<<dim3(BATCH * (OC / 2)), dim3(256), 0, stream>>>(x, weight, bias, out);
}